// Round 2
// baseline (155.890 us; speedup 1.0000x reference)
//
#include <hip/hip_runtime.h>

// Problem: N=512, D=512 pairwise scorer. ALL TENSORS float32 (per reference).
// left = E @ W1[:D], right = E @ W1[D:] + b1
// h[i,j,:] = left[i,:] + right[j,:] ; LayerNorm(D) ; GELU ; @W2 + b2 ; sigmoid
// out[i,j] = s[i,j] if i<=j else s[j,i]
//
// Key algebra: LN stats decompose. mu = mu_l[i]+mu_r[j];
// var = var_l[i] + var_r[j] + 2*cov(i,j), cov = (1/D) * lc @ rc^T (centered rows).
// Never materialize [N,N,D]; per pair one scalar rstd, then a chunkable k-loop:
// acc += gelu((lc+rc)*rstd*g[k]+b[k]) * w2[k]. Output symmetric -> compute only
// upper-triangle 16x16 tiles (528 blocks), mirror the store.

#define N_ 512
#define D_ 512

// ---------------- K1: left/right GEMMs ----------------
// 256 blocks: 64 row-groups (8 rows) x 4 col-groups (128 cols). 256 threads:
// t>>7 = half (0=left,1=right), t&127 = col within group. Each thread: 8 rows.
// W1 L2 traffic: 256 blocks * 512KB = 128MB (~4us at L2 rate).
__global__ __launch_bounds__(256) void k_gemm(const float* __restrict__ E,
                                              const float* __restrict__ W1,
                                              const float* __restrict__ b1,
                                              float* __restrict__ W /* [1024][512] */) {
    __shared__ float e[8][D_];
    const int t = threadIdx.x;
    const int br = blockIdx.x >> 2, bc = blockIdx.x & 3;
    const int r0 = br * 8, c0 = bc * 128;
    for (int x = t * 4; x < 8 * D_; x += 1024) {
        int r = x >> 9, c = x & (D_ - 1);
        *(float4*)&e[r][c] = *(const float4*)&E[(r0 + r) * D_ + c];
    }
    __syncthreads();
    const int half = t >> 7;
    const int col = c0 + (t & 127);
    const float* wp = W1 + (half << 18) + col;  // half*512*512 + col
    float a0 = 0.f, a1 = 0.f, a2 = 0.f, a3 = 0.f,
          a4 = 0.f, a5 = 0.f, a6 = 0.f, a7 = 0.f;
#pragma unroll 4
    for (int k = 0; k < D_; ++k) {
        float w = wp[k << 9];
        a0 = fmaf(e[0][k], w, a0); a1 = fmaf(e[1][k], w, a1);
        a2 = fmaf(e[2][k], w, a2); a3 = fmaf(e[3][k], w, a3);
        a4 = fmaf(e[4][k], w, a4); a5 = fmaf(e[5][k], w, a5);
        a6 = fmaf(e[6][k], w, a6); a7 = fmaf(e[7][k], w, a7);
    }
    const float bb = half ? b1[col] : 0.f;
    float* op = W + ((half << 9) + r0) * D_ + col;  // row (half*512 + r0), col
    op[0 * D_] = a0 + bb; op[1 * D_] = a1 + bb;
    op[2 * D_] = a2 + bb; op[3 * D_] = a3 + bb;
    op[4 * D_] = a4 + bb; op[5 * D_] = a5 + bb;
    op[6 * D_] = a6 + bb; op[7 * D_] = a7 + bb;
}

// ---------------- K2: center rows, compute per-row variance ----------------
__device__ __forceinline__ float block_sum(float v, float* sred, int t) {
#pragma unroll
    for (int off = 32; off > 0; off >>= 1) v += __shfl_xor(v, off, 64);
    int wave = t >> 6;
    if ((t & 63) == 0) sred[wave] = v;
    __syncthreads();
    float s = sred[0] + sred[1] + sred[2] + sred[3];
    __syncthreads();
    return s;
}

__global__ __launch_bounds__(256) void k_center(float* __restrict__ W,
                                                float* __restrict__ var) {
    __shared__ float sred[4];
    const int r = blockIdx.x, t = threadIdx.x;
    float* p = W + r * D_;
    float v0 = p[t], v1 = p[t + 256];
    float s = block_sum(v0 + v1, sred, t);
    float mean = s * (1.f / D_);
    float c0 = v0 - mean, c1 = v1 - mean;
    float ss = block_sum(c0 * c0 + c1 * c1, sred, t);
    p[t] = c0;
    p[t + 256] = c1;
    if (t == 0) var[r] = ss * (1.f / D_);
}

// ---------------- K3: fused cov -> rstd -> gelu-dot -> sigmoid ----------------
// 528 blocks = upper-triangle 16x16 pair tiles. 256 threads, one pair each.
// Pass A accumulates cov (per-pair rstd); pass B accumulates gelu-dot.
__device__ __forceinline__ void gelu_acc(float l, float r, float g, float be,
                                         float w, float rstd, float& acc) {
    // gelu_tanh(x) = x * sigmoid(1.5957691*(x + 0.044715 x^3))
    // exp arg in log2: q = x*(A*x^2 + B), B = -1.5957691*log2(e), A = B*0.044715
    float s = l + r;
    float x = fmaf(s * rstd, g, be);
    float x2 = x * x;
    float q = x * fmaf(-0.10294830f, x2, -2.30220935f);
    float eq = __builtin_amdgcn_exp2f(q);
    float ge = x * __builtin_amdgcn_rcpf(1.f + eq);
    acc = fmaf(ge, w, acc);
}

__global__ __launch_bounds__(256) void k_pair(const float* __restrict__ W,
                                              const float* __restrict__ var,
                                              const float* __restrict__ gf,
                                              const float* __restrict__ bef,
                                              const float* __restrict__ wf,
                                              const float* __restrict__ b2f,
                                              float* __restrict__ out) {
    __shared__ float ls[16][132];  // +4 pad: <=2-way bank alias (free on gfx950)
    __shared__ float rs[16][132];

    // decode upper-triangle tile index: b -> (I, J), I<=J, 32 tiles/dim
    const int b = blockIdx.x;
    int I = (int)((65.0f - sqrtf(4225.0f - 8.0f * (float)b)) * 0.5f);
    if (I < 0) I = 0;
    if (I > 31) I = 31;
#define S_(i) (32 * (i) - ((i) * ((i)-1)) / 2)
    while (S_(I) > b) --I;
    while (S_(I + 1) <= b) ++I;
    const int J = I + (b - S_(I));
#undef S_

    const int t = threadIdx.x;
    const int ti = t & 15, tj = t >> 4;
    const int gi = I * 16 + ti, gj = J * 16 + tj;
    const int Ibase = I * 16, Jbase = N_ + J * 16;

    // ---- pass A: cov ----
    float cov = 0.f;
    for (int kb = 0; kb < D_; kb += 128) {
        __syncthreads();
        for (int x = t; x < 512; x += 256) {
            int r = x >> 5, c4 = (x & 31) << 2;
            *(float4*)&ls[r][c4] = *(const float4*)&W[(Ibase + r) * D_ + kb + c4];
            *(float4*)&rs[r][c4] = *(const float4*)&W[(Jbase + r) * D_ + kb + c4];
        }
        __syncthreads();
#pragma unroll 8
        for (int k = 0; k < 128; k += 4) {
            float4 lv = *(float4*)&ls[ti][k];
            float4 rv = *(float4*)&rs[tj][k];
            cov += lv.x * rv.x + lv.y * rv.y + lv.z * rv.z + lv.w * rv.w;
        }
    }
    float varh = var[gi] + var[N_ + gj] + 2.f * cov * (1.f / D_);
    float rstd = rsqrtf(varh + 1e-5f);

    // ---- pass B: gelu dot ----
    float acc = 0.f;
    for (int kb = 0; kb < D_; kb += 128) {
        __syncthreads();
        for (int x = t; x < 512; x += 256) {
            int r = x >> 5, c4 = (x & 31) << 2;
            *(float4*)&ls[r][c4] = *(const float4*)&W[(Ibase + r) * D_ + kb + c4];
            *(float4*)&rs[r][c4] = *(const float4*)&W[(Jbase + r) * D_ + kb + c4];
        }
        __syncthreads();
#pragma unroll 4
        for (int k = 0; k < 128; k += 4) {
            float4 lv = *(float4*)&ls[ti][k];
            float4 rv = *(float4*)&rs[tj][k];
            float4 g4 = *(const float4*)&gf[kb + k];
            float4 be4 = *(const float4*)&bef[kb + k];
            float4 w4 = *(const float4*)&wf[kb + k];
            gelu_acc(lv.x, rv.x, g4.x, be4.x, w4.x, rstd, acc);
            gelu_acc(lv.y, rv.y, g4.y, be4.y, w4.y, rstd, acc);
            gelu_acc(lv.z, rv.z, g4.z, be4.z, w4.z, rstd, acc);
            gelu_acc(lv.w, rv.w, g4.w, be4.w, w4.w, rstd, acc);
        }
    }

    float z = acc + b2f[0];
    float sg = __builtin_amdgcn_rcpf(1.f + __builtin_amdgcn_exp2f(-1.44269504f * z));
    if (gi <= gj) {
        out[gi * N_ + gj] = sg;
        out[gj * N_ + gi] = sg;
    }
}

extern "C" void kernel_launch(void* const* d_in, const int* in_sizes, int n_in,
                              void* d_out, int out_size, void* d_ws, size_t ws_size,
                              hipStream_t stream) {
    const float* E     = (const float*)d_in[0];
    const float* W1    = (const float*)d_in[1];
    const float* b1    = (const float*)d_in[2];
    const float* gamma = (const float*)d_in[3];
    const float* beta  = (const float*)d_in[4];
    const float* w2    = (const float*)d_in[5];
    const float* b2    = (const float*)d_in[6];
    float* out = (float*)d_out;

    float* F    = (float*)d_ws;
    float* lcrc = F;                  // [1024][512] f32: rows 0..511 lc, 512..1023 rc(+b1)
    float* var  = F + 1024 * 512;     // [1024]

    k_gemm<<<256, 256, 0, stream>>>(E, W1, b1, lcrc);
    k_center<<<1024, 256, 0, stream>>>(lcrc, var);
    k_pair<<<528, 256, 0, stream>>>(lcrc, var, gamma, beta, w2, b2, out);
}

// Round 3
// 148.045 us; speedup vs baseline: 1.0530x; 1.0530x over previous
//
#include <hip/hip_runtime.h>

// N=512, D=512 pairwise scorer, all f32.
// left = E@W1[:D]; right = E@W1[D:]+b1; h = left[i]+right[j]; LN(D); GELU; @W2+b2; sigmoid.
// LN stats decompose: var = var_l[i]+var_r[j]+2*cov(i,j), cov = (1/D) lc@rc^T (centered).
// Never materialize [N,N,D]. Upper-triangle 16x16 pair tiles, mirrored store.

#define N_ 512
#define D_ 512

// ---------------- K1: left/right GEMMs (latency-optimized, no LDS) ----------------
// 512 blocks: bid = rowgrp(128 x 4rows) * 4 + half*2 + colgrp. 256 threads.
// Thread: 1 row x 4 cols. W1 via coalesced float4 (L2); E via wave-uniform
// scalar loads (readfirstlane -> SGPR base -> s_load broadcast). Unroll 16.
__global__ __launch_bounds__(256) void k_gemm(const float* __restrict__ E,
                                              const float* __restrict__ W1,
                                              const float* __restrict__ b1,
                                              float* __restrict__ W /* [1024][512] */) {
    const int t = threadIdx.x;
    const int colgrp = blockIdx.x & 1;
    const int half = (blockIdx.x >> 1) & 1;
    const int rowgrp = blockIdx.x >> 2;
    const int c = colgrp * 256 + (t & 63) * 4;
    // t>>6 is the wave index -> wave-uniform; force into SGPR for s_load path
    const int r = __builtin_amdgcn_readfirstlane(rowgrp * 4 + (t >> 6));
    const float* __restrict__ ep = E + r * D_;
    const float* __restrict__ wp = W1 + (half << 18) + c;  // row k at wp[k<<9]
    float4 acc = {0.f, 0.f, 0.f, 0.f};
#pragma unroll 16
    for (int k = 0; k < D_; ++k) {
        float4 w4 = *(const float4*)(wp + (k << 9));
        float e = ep[k];
        acc.x = fmaf(e, w4.x, acc.x);
        acc.y = fmaf(e, w4.y, acc.y);
        acc.z = fmaf(e, w4.z, acc.z);
        acc.w = fmaf(e, w4.w, acc.w);
    }
    if (half) {
        const float4 bb = *(const float4*)(b1 + c);
        acc.x += bb.x; acc.y += bb.y; acc.z += bb.z; acc.w += bb.w;
    }
    *(float4*)(W + ((half << 9) + r) * D_ + c) = acc;
}

// ---------------- K2: center rows, per-row variance ----------------
__device__ __forceinline__ float block_sum(float v, float* sred, int t) {
#pragma unroll
    for (int off = 32; off > 0; off >>= 1) v += __shfl_xor(v, off, 64);
    int wave = t >> 6;
    if ((t & 63) == 0) sred[wave] = v;
    __syncthreads();
    float s = sred[0] + sred[1] + sred[2] + sred[3];
    __syncthreads();
    return s;
}

__global__ __launch_bounds__(256) void k_center(float* __restrict__ W,
                                                float* __restrict__ var) {
    __shared__ float sred[4];
    const int r = blockIdx.x, t = threadIdx.x;
    float* p = W + r * D_;
    float v0 = p[t], v1 = p[t + 256];
    float s = block_sum(v0 + v1, sred, t);
    float mean = s * (1.f / D_);
    float c0 = v0 - mean, c1 = v1 - mean;
    float ss = block_sum(c0 * c0 + c1 * c1, sred, t);
    p[t] = c0;
    p[t + 256] = c1;
    if (t == 0) var[r] = ss * (1.f / D_);
}

// ---------------- K3: fused cov -> rstd -> gelu-dot -> sigmoid ----------------
// 528 blocks = upper-triangle 16x16 pair tiles, 256 threads, 1 pair each.
// Chunk = 256 k staged in LDS (stride 260: (260 mod 32)=4 -> conflict-free b128
// across the 16 rows). Pass A: cov; pass B: gelu dot.
#define CHUNK 256
#define LDP 260

__device__ __forceinline__ void gelu_acc(float l, float r, float g, float be,
                                         float w, float rstd, float& acc) {
    // gelu_tanh(x) = x * sigmoid(1.5957691*(x + 0.044715 x^3))
    // q = log2(exp(-2y)) = x*(A*x^2 + B), B = -2*log2e*0.79788456, A = B*0.044715
    float s = l + r;
    float x = fmaf(s * rstd, g, be);
    float x2 = x * x;
    float q = x * fmaf(-0.10294340f, x2, -2.30220935f);
    float eq = __builtin_amdgcn_exp2f(q);
    float ge = x * __builtin_amdgcn_rcpf(1.f + eq);
    acc = fmaf(ge, w, acc);
}

__global__ __launch_bounds__(256) void k_pair(const float* __restrict__ W,
                                              const float* __restrict__ var,
                                              const float* __restrict__ gf,
                                              const float* __restrict__ bef,
                                              const float* __restrict__ wf,
                                              const float* __restrict__ b2f,
                                              float* __restrict__ out) {
    __shared__ float ls[16][LDP];
    __shared__ float rs[16][LDP];

    // decode upper-triangle tile index b -> (I, J), I<=J, 32 tile-rows
    const int b = blockIdx.x;
    int I = (int)((65.0f - sqrtf(4225.0f - 8.0f * (float)b)) * 0.5f);
    if (I < 0) I = 0;
    if (I > 31) I = 31;
#define S_(i) (32 * (i) - ((i) * ((i)-1)) / 2)
    while (S_(I) > b) --I;
    while (S_(I + 1) <= b) ++I;
    const int J = I + (b - S_(I));
#undef S_

    const int t = threadIdx.x;
    const int ti = t & 15, tj = t >> 4;
    const int gi = I * 16 + ti, gj = J * 16 + tj;
    const int Ibase = I * 16, Jbase = N_ + J * 16;

    // ---- pass A: cov ----
    float cov = 0.f;
    for (int kb = 0; kb < D_; kb += CHUNK) {
        __syncthreads();
        for (int x = t; x < 16 * (CHUNK / 4); x += 256) {
            int r = x >> 6, c4 = (x & 63) << 2;
            *(float4*)&ls[r][c4] = *(const float4*)&W[(Ibase + r) * D_ + kb + c4];
            *(float4*)&rs[r][c4] = *(const float4*)&W[(Jbase + r) * D_ + kb + c4];
        }
        __syncthreads();
#pragma unroll 8
        for (int k = 0; k < CHUNK; k += 4) {
            float4 lv = *(float4*)&ls[ti][k];
            float4 rv = *(float4*)&rs[tj][k];
            cov += lv.x * rv.x + lv.y * rv.y + lv.z * rv.z + lv.w * rv.w;
        }
    }
    float varh = var[gi] + var[N_ + gj] + 2.f * cov * (1.f / D_);
    float rstd = rsqrtf(varh + 1e-5f);

    // ---- pass B: gelu dot ----
    float acc = 0.f;
    for (int kb = 0; kb < D_; kb += CHUNK) {
        __syncthreads();
        for (int x = t; x < 16 * (CHUNK / 4); x += 256) {
            int r = x >> 6, c4 = (x & 63) << 2;
            *(float4*)&ls[r][c4] = *(const float4*)&W[(Ibase + r) * D_ + kb + c4];
            *(float4*)&rs[r][c4] = *(const float4*)&W[(Jbase + r) * D_ + kb + c4];
        }
        __syncthreads();
#pragma unroll 4
        for (int k = 0; k < CHUNK; k += 4) {
            float4 lv = *(float4*)&ls[ti][k];
            float4 rv = *(float4*)&rs[tj][k];
            float4 g4 = *(const float4*)&gf[kb + k];
            float4 be4 = *(const float4*)&bef[kb + k];
            float4 w4 = *(const float4*)&wf[kb + k];
            gelu_acc(lv.x, rv.x, g4.x, be4.x, w4.x, rstd, acc);
            gelu_acc(lv.y, rv.y, g4.y, be4.y, w4.y, rstd, acc);
            gelu_acc(lv.z, rv.z, g4.z, be4.z, w4.z, rstd, acc);
            gelu_acc(lv.w, rv.w, g4.w, be4.w, w4.w, rstd, acc);
        }
    }

    float z = acc + b2f[0];
    float sg = __builtin_amdgcn_rcpf(1.f + __builtin_amdgcn_exp2f(-1.44269504f * z));
    if (gi <= gj) {
        out[gi * N_ + gj] = sg;
        out[gj * N_ + gi] = sg;
    }
}

extern "C" void kernel_launch(void* const* d_in, const int* in_sizes, int n_in,
                              void* d_out, int out_size, void* d_ws, size_t ws_size,
                              hipStream_t stream) {
    const float* E     = (const float*)d_in[0];
    const float* W1    = (const float*)d_in[1];
    const float* b1    = (const float*)d_in[2];
    const float* gamma = (const float*)d_in[3];
    const float* beta  = (const float*)d_in[4];
    const float* w2    = (const float*)d_in[5];
    const float* b2    = (const float*)d_in[6];
    float* out = (float*)d_out;

    float* F    = (float*)d_ws;
    float* lcrc = F;                  // [1024][512]: rows 0..511 lc, 512..1023 rc(+b1)
    float* var  = F + 1024 * 512;     // [1024]

    k_gemm<<<512, 256, 0, stream>>>(E, W1, b1, lcrc);
    k_center<<<1024, 256, 0, stream>>>(lcrc, var);
    k_pair<<<528, 256, 0, stream>>>(lcrc, var, gamma, beta, w2, b2, out);
}